// Round 1
// baseline (441.458 us; speedup 1.0000x reference)
//
#include <hip/hip_runtime.h>
#include <hip/hip_bf16.h>
#include <math.h>

typedef unsigned short u16;
typedef __attribute__((ext_vector_type(8))) short bf16x8;
typedef __attribute__((ext_vector_type(4))) float f32x4;

constexpr int D_ = 1024;
constexpr int H_ = 1365;
constexpr int E_ = 7;
constexpr int NTOK = 2048;
constexpr int HP = 1376;          // H padded to multiple of 32 (GEMM2 K dim)
constexpr int NE = 8;             // 7 routed + 1 shared
constexpr int SHARED_BASE = 4096; // routed slots = NTOK*2
constexpr int SLOTS = 6144;

// ctrl block (256B at ws offset 0): int view + float view
#define CI_COUNT 0
#define CI_OFF   8
#define CI_CUR   16
#define CF_PROB  32   // float index (byte 128)
#define CF_LSE2  40

constexpr size_t WS_CTRL = 0;
constexpr size_t WS_TIDX = 256;
constexpr size_t WS_TW   = WS_TIDX + (size_t)NTOK*2*sizeof(int);
constexpr size_t WS_STOK = WS_TW   + (size_t)NTOK*2*sizeof(float);
constexpr size_t WS_SW   = WS_STOK + (size_t)SLOTS*sizeof(int);
constexpr size_t WS_B1   = WS_SW   + (size_t)SLOTS*sizeof(float);
constexpr size_t WS_B2   = WS_B1   + (size_t)NE*H_*sizeof(float);
constexpr size_t WS_XB   = ((WS_B2 + (size_t)NE*D_*sizeof(float)) + 255) & ~(size_t)255;
constexpr size_t WS_W1B  = WS_XB  + (size_t)NTOK*D_*2;
constexpr size_t WS_W2B  = WS_W1B + (size_t)NE*H_*D_*2;
constexpr size_t WS_HEB  = WS_W2B + (size_t)NE*D_*HP*2;
constexpr size_t WS_END  = WS_HEB + (size_t)SLOTS*HP*2;   // ~66.2 MB

__device__ inline u16 f2bf(float f) {
    __hip_bfloat16 h = __float2bfloat16(f);
    return __builtin_bit_cast(u16, h);
}

// ---------------- convert fp32 -> bf16 staging buffers ----------------
__global__ void convert_kernel(const float* __restrict__ x,
                               const float* __restrict__ W1, const float* __restrict__ Ws1,
                               const float* __restrict__ W2, const float* __restrict__ Ws2,
                               const float* __restrict__ b1, const float* __restrict__ bs1,
                               const float* __restrict__ b2, const float* __restrict__ bs2,
                               u16* __restrict__ xb, u16* __restrict__ w1b, u16* __restrict__ w2b,
                               float* __restrict__ b1all, float* __restrict__ b2all)
{
    const size_t S0 = (size_t)NTOK*D_;
    const size_t S1 = (size_t)NE*H_*D_;
    const size_t S2 = (size_t)NE*D_*HP;
    const size_t S3 = (size_t)NE*H_;
    const size_t S4 = (size_t)NE*D_;
    const size_t total = S0+S1+S2+S3+S4;
    for (size_t i = blockIdx.x*(size_t)blockDim.x + threadIdx.x; i < total;
         i += (size_t)gridDim.x*blockDim.x) {
        size_t k = i;
        if (k < S0) { xb[k] = f2bf(x[k]); continue; }
        k -= S0;
        if (k < S1) {
            size_t e = k/((size_t)H_*D_), r = k - e*(size_t)H_*D_;
            w1b[k] = f2bf(e < 7 ? W1[e*(size_t)H_*D_ + r] : Ws1[r]);
            continue;
        }
        k -= S1;
        if (k < S2) {
            size_t e = k/((size_t)D_*HP), r = k - e*(size_t)D_*HP;
            size_t row = r/HP, h = r - row*HP;
            float v = 0.f;
            if (h < (size_t)H_) v = (e < 7) ? W2[e*(size_t)D_*H_ + row*H_ + h] : Ws2[row*H_ + h];
            w2b[k] = f2bf(v);
            continue;
        }
        k -= S2;
        if (k < S3) { size_t e = k/H_, j = k - e*H_; b1all[k] = (e<7) ? b1[k] : bs1[j]; continue; }
        k -= S3;
        { size_t e = k/D_, j = k - e*D_; b2all[k] = (e<7) ? b2[k] : bs2[j]; }
    }
}

// ---------------- router: fp32 logits, softmax, top-2, loss partials ----------------
__global__ void router_kernel(const float* __restrict__ x, const float* __restrict__ Wg,
                              int* __restrict__ ci, float* __restrict__ cf,
                              int* __restrict__ tidx, float* __restrict__ tw)
{
    int wid = threadIdx.x >> 6, lane = threadIdx.x & 63;
    int n = blockIdx.x*4 + wid;
    if (n >= NTOK) return;
    float p[E_] = {};
    const float* xr = x + (size_t)n*D_;
    for (int d = lane; d < D_; d += 64) {
        float xv = xr[d];
        #pragma unroll
        for (int e = 0; e < E_; e++) p[e] += xv * Wg[e*D_ + d];
    }
    #pragma unroll
    for (int e = 0; e < E_; e++) {
        float v = p[e];
        #pragma unroll
        for (int m = 32; m >= 1; m >>= 1) v += __shfl_xor(v, m);
        p[e] = v;
    }
    if (lane == 0) {
        float mx = p[0];
        #pragma unroll
        for (int e = 1; e < E_; e++) mx = fmaxf(mx, p[e]);
        float pr[E_], sum = 0.f;
        #pragma unroll
        for (int e = 0; e < E_; e++) { pr[e] = __expf(p[e]-mx); sum += pr[e]; }
        float lse = mx + logf(sum);
        int i0 = 0;
        #pragma unroll
        for (int e = 1; e < E_; e++) if (p[e] > p[i0]) i0 = e;
        int i1 = -1;
        #pragma unroll
        for (int e = 0; e < E_; e++) if (e != i0 && (i1 < 0 || p[e] > p[i1])) i1 = e;
        float g = expf(p[i1] - p[i0]);       // <= 1
        float w0 = 1.f/(1.f+g), w1 = g/(1.f+g);
        tidx[n*2] = i0; tidx[n*2+1] = i1;
        tw[n*2] = w0;  tw[n*2+1] = w1;
        atomicAdd(&ci[CI_COUNT+i0], 1);
        atomicAdd(&ci[CI_COUNT+i1], 1);
        float inv = 1.f/sum;
        #pragma unroll
        for (int e = 0; e < E_; e++) atomicAdd(&cf[CF_PROB+e], pr[e]*inv);
        atomicAdd(&cf[CF_LSE2], lse*lse);
    }
}

// ---------------- finalize: offsets + loss scalars ----------------
__global__ void finalize_kernel(int* __restrict__ ci, float* __restrict__ cf,
                                float* __restrict__ out)
{
    if (threadIdx.x == 0 && blockIdx.x == 0) {
        int off = 0;
        for (int e = 0; e < E_; e++) { ci[CI_OFF+e] = off; off += ci[CI_COUNT+e]; }
        ci[CI_OFF+7] = SHARED_BASE;
        ci[CI_COUNT+7] = NTOK;
        float la = 0.f;
        for (int e = 0; e < E_; e++)
            la += ((float)ci[CI_COUNT+e] / (float)(NTOK*2)) * (cf[CF_PROB+e] / (float)NTOK);
        out[(size_t)NTOK*D_]     = 0.01f * 7.f * la;
        out[(size_t)NTOK*D_ + 1] = 0.001f * cf[CF_LSE2] / (float)NTOK;
    }
}

// ---------------- scatter tokens into per-expert slot lists ----------------
__global__ void scatter_kernel(const int* __restrict__ tidx, const float* __restrict__ tw,
                               int* __restrict__ ci,
                               int* __restrict__ stok, float* __restrict__ sw)
{
    int n = blockIdx.x*blockDim.x + threadIdx.x;
    if (n >= NTOK) return;
    #pragma unroll
    for (int k = 0; k < 2; k++) {
        int e = tidx[n*2+k];
        int pos = atomicAdd(&ci[CI_CUR+e], 1);
        int s = ci[CI_OFF+e] + pos;
        stok[s] = n; sw[s] = tw[n*2+k];
    }
    stok[SHARED_BASE+n] = n; sw[SHARED_BASE+n] = 1.0f;
}

// ---------------- GEMM1: He = gelu(X_gather @ W1^T + b1), bf16 out ----------------
#define LDP 40
__global__ __launch_bounds__(256) void gemm1_kernel(
    const u16* __restrict__ xb, const u16* __restrict__ w1b,
    const float* __restrict__ b1all,
    const int* __restrict__ ci, const int* __restrict__ stok,
    u16* __restrict__ heb)
{
    __shared__ u16 As[64*LDP];
    __shared__ u16 Bs[64*LDP];
    int e = blockIdx.y >> 5, mt = blockIdx.y & 31, nt = blockIdx.x;
    int count = ci[CI_COUNT+e];
    int m0 = mt*64;
    if (m0 >= count) return;
    int offset = ci[CI_OFF+e];
    int valid = min(64, count - m0);

    int t = threadIdx.x;
    int lr = t >> 2, lk = (t & 3)*8;
    int tok = (lr < valid) ? stok[offset + m0 + lr] : -1;
    const u16* w1e = w1b + (size_t)e*H_*D_;
    int jglob = nt*64 + lr;
    bool jok = jglob < H_;

    int wid = t >> 6, lane = t & 63;
    int wm = (wid >> 1)*32, wn = (wid & 1)*32;
    int frow = lane & 15, fk = (lane >> 4)*8;
    f32x4 acc[2][2] = {};

    for (int ks = 0; ks < D_; ks += 32) {
        uint4 av = make_uint4(0,0,0,0), bv = make_uint4(0,0,0,0);
        if (tok >= 0) av = *(const uint4*)(xb + (size_t)tok*D_ + ks + lk);
        if (jok)      bv = *(const uint4*)(w1e + (size_t)jglob*D_ + ks + lk);
        __syncthreads();
        *(uint4*)&As[lr*LDP + lk] = av;
        *(uint4*)&Bs[lr*LDP + lk] = bv;
        __syncthreads();
        bf16x8 a0  = *(const bf16x8*)&As[(wm      + frow)*LDP + fk];
        bf16x8 a1  = *(const bf16x8*)&As[(wm + 16 + frow)*LDP + fk];
        bf16x8 b0  = *(const bf16x8*)&Bs[(wn      + frow)*LDP + fk];
        bf16x8 b1v = *(const bf16x8*)&Bs[(wn + 16 + frow)*LDP + fk];
        acc[0][0] = __builtin_amdgcn_mfma_f32_16x16x32_bf16(a0, b0,  acc[0][0], 0, 0, 0);
        acc[0][1] = __builtin_amdgcn_mfma_f32_16x16x32_bf16(a0, b1v, acc[0][1], 0, 0, 0);
        acc[1][0] = __builtin_amdgcn_mfma_f32_16x16x32_bf16(a1, b0,  acc[1][0], 0, 0, 0);
        acc[1][1] = __builtin_amdgcn_mfma_f32_16x16x32_bf16(a1, b1v, acc[1][1], 0, 0, 0);
    }
    #pragma unroll
    for (int mf = 0; mf < 2; mf++)
    #pragma unroll
    for (int nf = 0; nf < 2; nf++)
    #pragma unroll
    for (int r = 0; r < 4; r++) {
        int row = wm + mf*16 + (lane >> 4)*4 + r;
        int col = wn + nf*16 + (lane & 15);
        if (row < valid) {
            int gcol = nt*64 + col;
            if (gcol < HP) {
                float v = 0.f;
                if (gcol < H_) {
                    v = acc[mf][nf][r] + b1all[e*H_ + gcol];
                    v = 0.5f*v*(1.f + erff(v*0.70710678118f));
                }
                heb[(size_t)(offset + m0 + row)*HP + gcol] = f2bf(v);
            }
        }
    }
}

// ---------------- GEMM2: out[token] += w * (He @ W2^T + b2) ----------------
__global__ __launch_bounds__(256) void gemm2_kernel(
    const u16* __restrict__ heb, const u16* __restrict__ w2b,
    const float* __restrict__ b2all,
    const int* __restrict__ ci, const int* __restrict__ stok, const float* __restrict__ sw,
    float* __restrict__ out)
{
    __shared__ u16 As[64*LDP];
    __shared__ u16 Bs[64*LDP];
    int e = blockIdx.y >> 5, mt = blockIdx.y & 31, nt = blockIdx.x;
    int count = ci[CI_COUNT+e];
    int m0 = mt*64;
    if (m0 >= count) return;
    int offset = ci[CI_OFF+e];
    int valid = min(64, count - m0);

    int t = threadIdx.x;
    int lr = t >> 2, lk = (t & 3)*8;
    bool rok = lr < valid;
    const u16* arow_p = heb + (size_t)(offset + m0 + lr)*HP;
    const u16* w2e = w2b + (size_t)e*D_*HP;
    int jglob = nt*64 + lr;   // always < 1024

    int wid = t >> 6, lane = t & 63;
    int wm = (wid >> 1)*32, wn = (wid & 1)*32;
    int frow = lane & 15, fk = (lane >> 4)*8;
    f32x4 acc[2][2] = {};

    for (int ks = 0; ks < HP; ks += 32) {
        uint4 av = make_uint4(0,0,0,0);
        if (rok) av = *(const uint4*)(arow_p + ks + lk);
        uint4 bv = *(const uint4*)(w2e + (size_t)jglob*HP + ks + lk);
        __syncthreads();
        *(uint4*)&As[lr*LDP + lk] = av;
        *(uint4*)&Bs[lr*LDP + lk] = bv;
        __syncthreads();
        bf16x8 a0  = *(const bf16x8*)&As[(wm      + frow)*LDP + fk];
        bf16x8 a1  = *(const bf16x8*)&As[(wm + 16 + frow)*LDP + fk];
        bf16x8 b0  = *(const bf16x8*)&Bs[(wn      + frow)*LDP + fk];
        bf16x8 b1v = *(const bf16x8*)&Bs[(wn + 16 + frow)*LDP + fk];
        acc[0][0] = __builtin_amdgcn_mfma_f32_16x16x32_bf16(a0, b0,  acc[0][0], 0, 0, 0);
        acc[0][1] = __builtin_amdgcn_mfma_f32_16x16x32_bf16(a0, b1v, acc[0][1], 0, 0, 0);
        acc[1][0] = __builtin_amdgcn_mfma_f32_16x16x32_bf16(a1, b0,  acc[1][0], 0, 0, 0);
        acc[1][1] = __builtin_amdgcn_mfma_f32_16x16x32_bf16(a1, b1v, acc[1][1], 0, 0, 0);
    }
    #pragma unroll
    for (int mf = 0; mf < 2; mf++)
    #pragma unroll
    for (int nf = 0; nf < 2; nf++)
    #pragma unroll
    for (int r = 0; r < 4; r++) {
        int row = wm + mf*16 + (lane >> 4)*4 + r;
        int col = wn + nf*16 + (lane & 15);
        if (row < valid) {
            int slot = offset + m0 + row;
            int tok = stok[slot];
            float w = sw[slot];
            int gcol = nt*64 + col;
            float v = acc[mf][nf][r] + b2all[e*D_ + gcol];
            atomicAdd(&out[(size_t)tok*D_ + gcol], w*v);
        }
    }
}

extern "C" void kernel_launch(void* const* d_in, const int* in_sizes, int n_in,
                              void* d_out, int out_size, void* d_ws, size_t ws_size,
                              hipStream_t stream)
{
    const float* x   = (const float*)d_in[0];
    const float* Wg  = (const float*)d_in[1];
    const float* W1  = (const float*)d_in[2];
    const float* b1  = (const float*)d_in[3];
    const float* W2  = (const float*)d_in[4];
    const float* b2  = (const float*)d_in[5];
    const float* Ws1 = (const float*)d_in[6];
    const float* bs1 = (const float*)d_in[7];
    const float* Ws2 = (const float*)d_in[8];
    const float* bs2 = (const float*)d_in[9];
    float* out = (float*)d_out;
    char* ws = (char*)d_ws;

    int*   ci    = (int*)(ws + WS_CTRL);
    float* cf    = (float*)(ws + WS_CTRL);
    int*   tidx  = (int*)(ws + WS_TIDX);
    float* tw    = (float*)(ws + WS_TW);
    int*   stok  = (int*)(ws + WS_STOK);
    float* sw    = (float*)(ws + WS_SW);
    float* b1all = (float*)(ws + WS_B1);
    float* b2all = (float*)(ws + WS_B2);
    u16*   xb    = (u16*)(ws + WS_XB);
    u16*   w1b   = (u16*)(ws + WS_W1B);
    u16*   w2b   = (u16*)(ws + WS_W2B);
    u16*   heb   = (u16*)(ws + WS_HEB);

    hipMemsetAsync(ws + WS_CTRL, 0, 256, stream);
    hipMemsetAsync(d_out, 0, (size_t)out_size*sizeof(float), stream);

    convert_kernel<<<2048, 256, 0, stream>>>(x, W1, Ws1, W2, Ws2, b1, bs1, b2, bs2,
                                             xb, w1b, w2b, b1all, b2all);
    router_kernel<<<NTOK/4, 256, 0, stream>>>(x, Wg, ci, cf, tidx, tw);
    finalize_kernel<<<1, 64, 0, stream>>>(ci, cf, out);
    scatter_kernel<<<(NTOK+255)/256, 256, 0, stream>>>(tidx, tw, ci, stok, sw);

    dim3 g1((HP+63)/64, NE*32);   // 22 x 256
    gemm1_kernel<<<g1, 256, 0, stream>>>(xb, w1b, b1all, ci, stok, heb);
    dim3 g2(D_/64, NE*32);        // 16 x 256
    gemm2_kernel<<<g2, 256, 0, stream>>>(heb, w2b, b2all, ci, stok, sw, out);
}

// Round 2
// 214.432 us; speedup vs baseline: 2.0587x; 2.0587x over previous
//
#include <hip/hip_runtime.h>
#include <hip/hip_bf16.h>
#include <math.h>

typedef unsigned short u16;
typedef __attribute__((ext_vector_type(8))) short bf16x8;
typedef __attribute__((ext_vector_type(4))) float f32x4;

constexpr int D_ = 1024;
constexpr int H_ = 1365;
constexpr int E_ = 7;
constexpr int NTOK = 2048;
constexpr int HP = 1376;          // H padded to multiple of 32 (GEMM2 K dim)
constexpr int NE = 8;             // 7 routed + 1 shared
constexpr int SHARED_BASE = 4096; // routed slots = NTOK*2
constexpr int SLOTS = 6144;

#define CI_COUNT 0
#define CI_OFF   8

constexpr size_t WS_CTRL = 0;
constexpr size_t WS_TIDX = 256;
constexpr size_t WS_TW   = WS_TIDX + (size_t)NTOK*2*sizeof(int);
constexpr size_t WS_PROB = WS_TW   + (size_t)NTOK*2*sizeof(float);
constexpr size_t WS_LSE2 = WS_PROB + (size_t)NTOK*8*sizeof(float);
constexpr size_t WS_STOK = WS_LSE2 + (size_t)NTOK*sizeof(float);
constexpr size_t WS_SW   = WS_STOK + (size_t)SLOTS*sizeof(int);
constexpr size_t WS_B1   = WS_SW   + (size_t)SLOTS*sizeof(float);
constexpr size_t WS_B2   = WS_B1   + (size_t)NE*H_*sizeof(float);
constexpr size_t WS_XB   = ((WS_B2 + (size_t)NE*D_*sizeof(float)) + 255) & ~(size_t)255;
constexpr size_t WS_W1B  = WS_XB  + (size_t)NTOK*D_*2;
constexpr size_t WS_W2B  = WS_W1B + (size_t)NE*H_*D_*2;
constexpr size_t WS_HEB  = WS_W2B + (size_t)NE*D_*HP*2;
constexpr size_t WS_END  = WS_HEB + (size_t)SLOTS*HP*2;   // ~63.2 MiB

__device__ __forceinline__ u16 f2bf(float f) {
    __hip_bfloat16 h = __float2bfloat16(f);
    return __builtin_bit_cast(u16, h);
}

__device__ __forceinline__ void gload_lds16(const u16* g, u16* l) {
    __builtin_amdgcn_global_load_lds(
        (const __attribute__((address_space(1))) void*)g,
        (__attribute__((address_space(3))) void*)l, 16, 0, 0);
}

__device__ __forceinline__ uint4 pack8(float4 a, float4 b) {
    union { u16 h[8]; uint4 v; } u;
    u.h[0]=f2bf(a.x); u.h[1]=f2bf(a.y); u.h[2]=f2bf(a.z); u.h[3]=f2bf(a.w);
    u.h[4]=f2bf(b.x); u.h[5]=f2bf(b.y); u.h[6]=f2bf(b.z); u.h[7]=f2bf(b.w);
    return u.v;
}

// ---------------- convert fp32 -> bf16 staging buffers (vectorized) ----------------
__global__ void convert_kernel(const float* __restrict__ x,
                               const float* __restrict__ W1, const float* __restrict__ Ws1,
                               const float* __restrict__ W2, const float* __restrict__ Ws2,
                               const float* __restrict__ b1, const float* __restrict__ bs1,
                               const float* __restrict__ b2, const float* __restrict__ bs2,
                               u16* __restrict__ xb, u16* __restrict__ w1b, u16* __restrict__ w2b,
                               float* __restrict__ b1all, float* __restrict__ b2all)
{
    const size_t G0 = (size_t)NTOK*D_/8;          // xb groups
    const size_t G1 = (size_t)NE*H_*D_/8;         // w1b groups (W1 flat then Ws1 flat)
    const size_t G2 = (size_t)NE*D_*HP/8;         // w2b groups
    const size_t W1FLAT = (size_t)7*H_*D_;        // divisible by 8
    const size_t SB = (size_t)NE*H_ + (size_t)NE*D_;
    const size_t total = G0+G1+G2+SB;
    for (size_t i = blockIdx.x*(size_t)blockDim.x + threadIdx.x; i < total;
         i += (size_t)gridDim.x*blockDim.x) {
        size_t k = i;
        if (k < G0) {
            const float4* s = (const float4*)x + k*2;
            ((uint4*)xb)[k] = pack8(s[0], s[1]);
            continue;
        }
        k -= G0;
        if (k < G1) {
            size_t base = k*8;
            const float* src = (base < W1FLAT) ? (W1 + base) : (Ws1 + (base - W1FLAT));
            const float4* s = (const float4*)src;
            ((uint4*)w1b)[k] = pack8(s[0], s[1]);
            continue;
        }
        k -= G1;
        if (k < G2) {
            size_t base = k*8;                     // dest elem index in [NE][D_][HP]
            size_t e = base/((size_t)D_*HP);
            size_t rr = base - e*(size_t)D_*HP;
            size_t drow = rr/HP, h0 = rr - drow*HP;
            const float* srow = (e < 7) ? (W2 + ((size_t)e*D_ + drow)*H_)
                                        : (Ws2 + drow*(size_t)H_);
            union { u16 h[8]; uint4 v; } u;
            #pragma unroll
            for (int q = 0; q < 8; q++) {
                size_t h = h0 + q;
                u.h[q] = (h < (size_t)H_) ? f2bf(srow[h]) : (u16)0;
            }
            ((uint4*)w2b)[k] = u.v;
            continue;
        }
        k -= G2;
        if (k < (size_t)NE*H_) {
            size_t e = k/H_, j = k - e*H_;
            b1all[k] = (e < 7) ? b1[k] : bs1[j];
        } else {
            size_t kk = k - (size_t)NE*H_;
            size_t e = kk/D_, j = kk - e*D_;
            b2all[kk] = (e < 7) ? b2[kk] : bs2[j];
        }
    }
}

// ---------------- router: fp32 logits, softmax, top-2 (NO global atomics) ----------------
__global__ void router_kernel(const float* __restrict__ x, const float* __restrict__ Wg,
                              int* __restrict__ tidx, float* __restrict__ tw,
                              float* __restrict__ probs, float* __restrict__ lse2)
{
    int wid = threadIdx.x >> 6, lane = threadIdx.x & 63;
    int n = blockIdx.x*4 + wid;
    if (n >= NTOK) return;
    float p[E_] = {};
    const float* xr = x + (size_t)n*D_;
    for (int d0 = lane*4; d0 < D_; d0 += 256) {
        float4 xv = *(const float4*)(xr + d0);
        #pragma unroll
        for (int e = 0; e < E_; e++) {
            float4 wv = *(const float4*)(Wg + e*D_ + d0);
            p[e] += xv.x*wv.x + xv.y*wv.y + xv.z*wv.z + xv.w*wv.w;
        }
    }
    #pragma unroll
    for (int e = 0; e < E_; e++) {
        float v = p[e];
        #pragma unroll
        for (int m = 32; m >= 1; m >>= 1) v += __shfl_xor(v, m);
        p[e] = v;
    }
    if (lane == 0) {
        float mx = p[0];
        #pragma unroll
        for (int e = 1; e < E_; e++) mx = fmaxf(mx, p[e]);
        float pr[E_], sum = 0.f;
        #pragma unroll
        for (int e = 0; e < E_; e++) { pr[e] = __expf(p[e]-mx); sum += pr[e]; }
        float lse = mx + logf(sum);
        int i0 = 0;
        #pragma unroll
        for (int e = 1; e < E_; e++) if (p[e] > p[i0]) i0 = e;
        int i1 = -1;
        #pragma unroll
        for (int e = 0; e < E_; e++) if (e != i0 && (i1 < 0 || p[e] > p[i1])) i1 = e;
        float g = expf(p[i1] - p[i0]);       // <= 1
        tidx[n*2] = i0; tidx[n*2+1] = i1;
        tw[n*2] = 1.f/(1.f+g); tw[n*2+1] = g/(1.f+g);
        float inv = 1.f/sum;
        #pragma unroll
        for (int e = 0; e < E_; e++) probs[n*8+e] = pr[e]*inv;
        lse2[n] = lse*lse;
    }
}

// ---------------- finalize: counts, offsets, loss, deterministic scatter ----------------
__global__ __launch_bounds__(512) void finalize_kernel(
    const int* __restrict__ tidx, const float* __restrict__ tw,
    const float* __restrict__ probs, const float* __restrict__ lse2,
    int* __restrict__ ci, int* __restrict__ stok, float* __restrict__ sw,
    float* __restrict__ out)
{
    __shared__ int lt[NTOK*2];
    __shared__ float psum[8];
    __shared__ float lsumS;
    __shared__ int cntS[8], offS[8];
    int t = threadIdx.x;
    if (t < 8) { psum[t] = 0.f; cntS[t] = 0; }
    if (t == 0) lsumS = 0.f;
    for (int i = t; i < NTOK*2; i += 512) lt[i] = tidx[i];
    __syncthreads();
    float lp[E_] = {}; float ll = 0.f;
    for (int n = t; n < NTOK; n += 512) {
        #pragma unroll
        for (int e = 0; e < E_; e++) lp[e] += probs[n*8+e];
        ll += lse2[n];
    }
    #pragma unroll
    for (int e = 0; e < E_; e++) atomicAdd(&psum[e], lp[e]);
    atomicAdd(&lsumS, ll);
    int wid = t >> 6, lane = t & 63;
    if (wid < 7) {
        int c = 0;
        for (int i = lane; i < NTOK*2; i += 64) c += (lt[i] == wid) ? 1 : 0;
        #pragma unroll
        for (int m = 32; m >= 1; m >>= 1) c += __shfl_xor(c, m);
        if (lane == 0) cntS[wid] = c;
    }
    __syncthreads();
    if (t == 0) {
        int o = 0;
        for (int e = 0; e < E_; e++) { offS[e] = o; o += cntS[e]; }
        offS[7] = SHARED_BASE; cntS[7] = NTOK;
        float la = 0.f;
        for (int e = 0; e < E_; e++)
            la += ((float)cntS[e] / (float)(NTOK*2)) * (psum[e] / (float)NTOK);
        out[(size_t)NTOK*D_]     = 0.01f * 7.f * la;
        out[(size_t)NTOK*D_ + 1] = 0.001f * lsumS / (float)NTOK;
        #pragma unroll
        for (int e = 0; e < 8; e++) { ci[CI_COUNT+e] = cntS[e]; ci[CI_OFF+e] = offS[e]; }
    }
    __syncthreads();
    if (wid < 7) {
        int base = offS[wid], run = 0;
        for (int c0 = 0; c0 < NTOK*2; c0 += 64) {
            bool m = (lt[c0 + lane] == wid);
            unsigned long long bal = __ballot(m);
            int pre = __popcll(bal & ((1ull << lane) - 1ull));
            if (m) {
                int i = c0 + lane;
                int s = base + run + pre;
                stok[s] = i >> 1; sw[s] = tw[i];
            }
            run += __popcll(bal);
        }
    } else {
        for (int n = lane; n < NTOK; n += 64) {
            stok[SHARED_BASE+n] = n; sw[SHARED_BASE+n] = 1.f;
        }
    }
}

// ---------------- GEMM kernels: 128x128 tile, BK=32, global_load_lds ----------------
#define BM 128
#define BN 128
#define BK 32

__global__ __launch_bounds__(256) void gemm1_kernel(
    const u16* __restrict__ xb, const u16* __restrict__ w1b,
    const float* __restrict__ b1all,
    const int* __restrict__ ci, const int* __restrict__ stok,
    u16* __restrict__ heb)
{
    __shared__ u16 As[BM*BK];
    __shared__ u16 Bs[BN*BK];
    int e = blockIdx.y >> 5, mt = blockIdx.y & 31, nt = blockIdx.x;
    int count = ci[CI_COUNT+e];
    int m0 = mt*BM;
    if (m0 >= count) return;
    int offset = ci[CI_OFF+e];
    int valid = min(BM, count - m0);

    int t = threadIdx.x, wid = t >> 6, lane = t & 63;
    int colE = (lane & 3)*8;
    const u16* w1e = w1b + (size_t)e*H_*D_;

    const u16* aSrc[2]; const u16* bSrc[2];
    u16* aDst[2]; u16* bDst[2];
    #pragma unroll
    for (int j = 0; j < 2; j++) {
        int row = (wid*2+j)*16 + (lane >> 2);
        int ar = min(row, valid-1);
        int tok = stok[offset + m0 + ar];
        aSrc[j] = xb + (size_t)tok*D_ + colE;
        int jg = nt*BN + row; if (jg > H_-1) jg = H_-1;
        bSrc[j] = w1e + (size_t)jg*D_ + colE;
        aDst[j] = &As[(wid*2+j)*512];
        bDst[j] = &Bs[(wid*2+j)*512];
    }

    int wm = (wid >> 1)*64, wn = (wid & 1)*64;
    int frow = lane & 15, fk = (lane >> 4)*8;
    f32x4 acc[4][4] = {};

    for (int ks = 0; ks < D_; ks += BK) {
        __syncthreads();
        #pragma unroll
        for (int j = 0; j < 2; j++) {
            gload_lds16(aSrc[j] + ks, aDst[j]);
            gload_lds16(bSrc[j] + ks, bDst[j]);
        }
        __syncthreads();
        bf16x8 af[4], bf[4];
        #pragma unroll
        for (int mf = 0; mf < 4; mf++) af[mf] = *(const bf16x8*)&As[(wm+mf*16+frow)*BK + fk];
        #pragma unroll
        for (int nf = 0; nf < 4; nf++) bf[nf] = *(const bf16x8*)&Bs[(wn+nf*16+frow)*BK + fk];
        #pragma unroll
        for (int mf = 0; mf < 4; mf++)
            #pragma unroll
            for (int nf = 0; nf < 4; nf++)
                acc[mf][nf] = __builtin_amdgcn_mfma_f32_16x16x32_bf16(af[mf], bf[nf], acc[mf][nf], 0, 0, 0);
    }

    int r4 = (lane >> 4)*4, cEl = lane & 15;
    #pragma unroll
    for (int mf = 0; mf < 4; mf++) {
        #pragma unroll
        for (int r = 0; r < 4; r++) {
            int row = wm + mf*16 + r4 + r;
            if (row < valid) {
                size_t rbase = (size_t)(offset + m0 + row)*HP;
                #pragma unroll
                for (int nf = 0; nf < 4; nf++) {
                    int gcol = nt*BN + wn + nf*16 + cEl;
                    if (gcol < HP) {
                        float v = 0.f;
                        if (gcol < H_) {
                            v = acc[mf][nf][r] + b1all[e*H_ + gcol];
                            v = 0.5f*v*(1.f + erff(v*0.70710678118f));
                        }
                        heb[rbase + gcol] = f2bf(v);
                    }
                }
            }
        }
    }
}

__global__ __launch_bounds__(256) void gemm2_kernel(
    const u16* __restrict__ heb, const u16* __restrict__ w2b,
    const float* __restrict__ b2all,
    const int* __restrict__ ci, const int* __restrict__ stok, const float* __restrict__ sw,
    float* __restrict__ out)
{
    __shared__ u16 As[BM*BK];
    __shared__ u16 Bs[BN*BK];
    int e = blockIdx.y >> 5, mt = blockIdx.y & 31, nt = blockIdx.x;
    int count = ci[CI_COUNT+e];
    int m0 = mt*BM;
    if (m0 >= count) return;
    int offset = ci[CI_OFF+e];
    int valid = min(BM, count - m0);

    int t = threadIdx.x, wid = t >> 6, lane = t & 63;
    int colE = (lane & 3)*8;
    const u16* w2e = w2b + (size_t)e*D_*HP;

    const u16* aSrc[2]; const u16* bSrc[2];
    u16* aDst[2]; u16* bDst[2];
    #pragma unroll
    for (int j = 0; j < 2; j++) {
        int row = (wid*2+j)*16 + (lane >> 2);
        int slot = offset + m0 + row;
        if (slot > SLOTS-1) slot = SLOTS-1;
        aSrc[j] = heb + (size_t)slot*HP + colE;
        int jg = nt*BN + row;                 // N=1024 exact, always valid
        bSrc[j] = w2e + (size_t)jg*HP + colE;
        aDst[j] = &As[(wid*2+j)*512];
        bDst[j] = &Bs[(wid*2+j)*512];
    }

    int wm = (wid >> 1)*64, wn = (wid & 1)*64;
    int frow = lane & 15, fk = (lane >> 4)*8;
    f32x4 acc[4][4] = {};

    for (int ks = 0; ks < HP; ks += BK) {     // 43 iterations
        __syncthreads();
        #pragma unroll
        for (int j = 0; j < 2; j++) {
            gload_lds16(aSrc[j] + ks, aDst[j]);
            gload_lds16(bSrc[j] + ks, bDst[j]);
        }
        __syncthreads();
        bf16x8 af[4], bf[4];
        #pragma unroll
        for (int mf = 0; mf < 4; mf++) af[mf] = *(const bf16x8*)&As[(wm+mf*16+frow)*BK + fk];
        #pragma unroll
        for (int nf = 0; nf < 4; nf++) bf[nf] = *(const bf16x8*)&Bs[(wn+nf*16+frow)*BK + fk];
        #pragma unroll
        for (int mf = 0; mf < 4; mf++)
            #pragma unroll
            for (int nf = 0; nf < 4; nf++)
                acc[mf][nf] = __builtin_amdgcn_mfma_f32_16x16x32_bf16(af[mf], bf[nf], acc[mf][nf], 0, 0, 0);
    }

    int r4 = (lane >> 4)*4, cEl = lane & 15;
    #pragma unroll
    for (int mf = 0; mf < 4; mf++) {
        #pragma unroll
        for (int r = 0; r < 4; r++) {
            int row = wm + mf*16 + r4 + r;
            if (row < valid) {
                int slot = offset + m0 + row;
                int tok = stok[slot];
                float w = sw[slot];
                #pragma unroll
                for (int nf = 0; nf < 4; nf++) {
                    int gcol = nt*BN + wn + nf*16 + cEl;
                    float v = acc[mf][nf][r] + b2all[e*D_ + gcol];
                    atomicAdd(&out[(size_t)tok*D_ + gcol], w*v);
                }
            }
        }
    }
}

extern "C" void kernel_launch(void* const* d_in, const int* in_sizes, int n_in,
                              void* d_out, int out_size, void* d_ws, size_t ws_size,
                              hipStream_t stream)
{
    const float* x   = (const float*)d_in[0];
    const float* Wg  = (const float*)d_in[1];
    const float* W1  = (const float*)d_in[2];
    const float* b1  = (const float*)d_in[3];
    const float* W2  = (const float*)d_in[4];
    const float* b2  = (const float*)d_in[5];
    const float* Ws1 = (const float*)d_in[6];
    const float* bs1 = (const float*)d_in[7];
    const float* Ws2 = (const float*)d_in[8];
    const float* bs2 = (const float*)d_in[9];
    float* out = (float*)d_out;
    char* ws = (char*)d_ws;

    int*   ci    = (int*)(ws + WS_CTRL);
    int*   tidx  = (int*)(ws + WS_TIDX);
    float* tw    = (float*)(ws + WS_TW);
    float* probs = (float*)(ws + WS_PROB);
    float* lse2  = (float*)(ws + WS_LSE2);
    int*   stok  = (int*)(ws + WS_STOK);
    float* sw    = (float*)(ws + WS_SW);
    float* b1all = (float*)(ws + WS_B1);
    float* b2all = (float*)(ws + WS_B2);
    u16*   xb    = (u16*)(ws + WS_XB);
    u16*   w1b   = (u16*)(ws + WS_W1B);
    u16*   w2b   = (u16*)(ws + WS_W2B);
    u16*   heb   = (u16*)(ws + WS_HEB);

    hipMemsetAsync(d_out, 0, (size_t)out_size*sizeof(float), stream);

    convert_kernel<<<2048, 256, 0, stream>>>(x, W1, Ws1, W2, Ws2, b1, bs1, b2, bs2,
                                             xb, w1b, w2b, b1all, b2all);
    router_kernel<<<NTOK/4, 256, 0, stream>>>(x, Wg, tidx, tw, probs, lse2);
    finalize_kernel<<<1, 512, 0, stream>>>(tidx, tw, probs, lse2, ci, stok, sw, out);

    dim3 g1((HP+BN-1)/BN, NE*32);   // 11 x 256
    gemm1_kernel<<<g1, 256, 0, stream>>>(xb, w1b, b1all, ci, stok, heb);
    dim3 g2(D_/BN, NE*32);          // 8 x 256
    gemm2_kernel<<<g2, 256, 0, stream>>>(heb, w2b, b2all, ci, stok, sw, out);
}